// Round 21
// baseline (1563.948 us; speedup 1.0000x reference)
//
#include <hip/hip_runtime.h>

#define NB 8192
#define NT 512

typedef unsigned int u32;
typedef unsigned short u16;
typedef float f32x4 __attribute__((ext_vector_type(4)));
typedef u32 u32x4 __attribute__((ext_vector_type(4)));
typedef _Float16 h16x2 __attribute__((ext_vector_type(2)));

__device__ __forceinline__ float rcp_(float x){ return __builtin_amdgcn_rcpf(x); }
__device__ __forceinline__ float exp2_(float x){ return __builtin_amdgcn_exp2f(x); }
__device__ __forceinline__ float tanh_(float x){ return 1.0f - 2.0f*rcp_(1.0f + exp2_(2.88539008177792681f*x)); }
__device__ __forceinline__ float sigm(float x){ return rcp_(1.0f + exp2_(-1.44269504088896341f*x)); }

#define PINF(v)  asm volatile("" : "+v"(v))

// quad_perm DPP (dst lane k reads src lane p_k within its quad)
#define QP_XOR1 0xB1   // [1,0,3,2]
#define QP_BC0  0x00   // all read quad-lane 0
#define QP_BC2  0xAA   // all read quad-lane 2
template<int C>
__device__ __forceinline__ u32 dppu(u32 x){
    return (u32)__builtin_amdgcn_update_dpp(0, (int)x, C, 0xF, 0xF, true);
}
__device__ __forceinline__ float dpp_xor1(float x){
    return __int_as_float(__builtin_amdgcn_update_dpp(0, __float_as_int(x), QP_XOR1, 0xF, 0xF, true));
}
// lane^4 exchange, pure VALU (validated R10/R11/R12)
__device__ __forceinline__ u32 swz4u(u32 x){
    int v = __builtin_amdgcn_update_dpp((int)x, (int)x, 0x104, 0xF, 0x5, false);
    v     = __builtin_amdgcn_update_dpp(v,      (int)x, 0x114, 0xF, 0xA, false);
    return (u32)v;
}
// group8 broadcast via LDS swizzle (validated R17) - used only in cold epilogue
template<int J>
__device__ __forceinline__ float swzbc(float x){
    return __int_as_float(__builtin_amdgcn_ds_swizzle(__float_as_int(x), (J<<5)|0x18));
}

__device__ __forceinline__ float upkh(u16 v){ _Float16 h; __builtin_memcpy(&h,&v,2); return (float)h; }
__device__ __forceinline__ float upk_lo(u32 v){ return upkh((u16)(v&0xffffu)); }
__device__ __forceinline__ float upk_hi(u32 v){ return upkh((u16)(v>>16)); }
__device__ __forceinline__ u32 pkrtz(float a, float b){
    auto p = __builtin_amdgcn_cvt_pkrtz(a, b);
    return __builtin_bit_cast(u32, p);
}
__device__ __forceinline__ float dot2f(h16x2 a, h16x2 b, float c){
#if __has_builtin(__builtin_amdgcn_fdot2)
    return __builtin_amdgcn_fdot2(a, b, c, false);
#else
    return fmaf((float)a.x, (float)b.x, fmaf((float)a.y, (float)b.y, c));
#endif
}
__device__ __forceinline__ float dot2u(u32 w, u32 d, float c){
    return dot2f(__builtin_bit_cast(h16x2, w), __builtin_bit_cast(h16x2, d), c);
}

// ---------------------------------------------------------------------------
// Lane-local-gates (R17) + pure-VALU broadcast (this round):
//   hp = pkrtz(hn, dpp_xor1(hn))   // lanes 0/2/4(/6): pairs A=(h0,h1)/B/C/C
//   u = QP_BC0(hp)  -> lanes0-3: A, lanes4-7: C
//   v = QP_BC2(hp)  -> lanes0-3: B, lanes4-7: C
//   w = swz4(u)     -> lanes0-3: C, lanes4-7: A
//   z = swz4(v)     -> lanes0-3: C, lanes4-7: B
//   d01 = hi4?w:u ; d23 = hi4?z:v ; d45 = hi4?u:w     (hi4 = lane&4)
// Zero LDS ops in the recurrence. Buffers quad-packed: 48B per (t-quad,seq):
//   [h01@t0..t3][h23@t0..t3][h45@t0..t3]  (fp16 pair dwords, t ascending)
// ---------------------------------------------------------------------------

#define BCAST(hn, d01, d23, d45) do{                     \
    const float _hx = dpp_xor1(hn);                      \
    const u32 _hp = pkrtz((hn), _hx);                    \
    const u32 _u = dppu<QP_BC0>(_hp);                    \
    const u32 _v = dppu<QP_BC2>(_hp);                    \
    const u32 _w = swz4u(_u);                            \
    const u32 _z = swz4u(_v);                            \
    d01 = hi4 ? _w : _u;                                 \
    d23 = hi4 ? _z : _v;                                 \
    d45 = hi4 ? _u : _w;                                 \
}while(0)

// Layer 0, both directions. 2048 blocks x 64 = 2048 waves (2/SIMD).
__global__ __launch_bounds__(64)
__attribute__((amdgpu_waves_per_eu(2,2)))
void lstm_l0v3(
    const float* __restrict__ x,
    const float* __restrict__ h0, const float* __restrict__ c0,
    const float* __restrict__ Wf, const float* __restrict__ Uf, const float* __restrict__ bf,
    const float* __restrict__ Wb, const float* __restrict__ Ub, const float* __restrict__ bbv,
    char* __restrict__ fbuf, char* __restrict__ bbuf)
{
    const int l  = threadIdx.x;
    const int j  = l & 7;
    const int jj = (j < 6) ? j : (j - 2);
    const bool hi4 = (j & 4) != 0;
    const int e  = blockIdx.x*8 + (l >> 3);
    const int b  = e & (NB-1);
    const int dir = e >> 13;

    const float* W  = dir ? Wb  : Wf;
    const float* U  = dir ? Ub  : Uf;
    const float* bi = dir ? bbv : bf;

    u32 wd[4][6]; float cEb[4];
#pragma unroll
    for (int g=0; g<4; ++g){
        const int row = g*6 + jj;
        const float cs = (g==2) ? -2.88539008177792681f : -1.44269504088896341f;
#pragma unroll
        for (int k=0;k<3;++k) wd[g][k]   = pkrtz(cs*W[row*6+2*k], cs*W[row*6+2*k+1]);
#pragma unroll
        for (int k=0;k<3;++k) wd[g][3+k] = pkrtz(cs*U[row*6+2*k], cs*U[row*6+2*k+1]);
        cEb[g] = cs * bi[row];
    }
#pragma unroll
    for (int g=0; g<4; ++g){
#pragma unroll
        for (int k=0;k<6;++k) PINF(wd[g][k]);
        PINF(cEb[g]);
    }

    float cc = c0[dir*(NB*6) + b*6 + jj];
    float hn = h0[dir*(NB*6) + b*6 + jj];
    u32 d01, d23, d45;
    BCAST(hn, d01, d23, d45);

    const char* xb = (const char*)(x + (size_t)b*(NT*6));
    char* obase = (dir ? bbuf : fbuf) + (size_t)b*48 + j*16;   // used when j<3
    const size_t qstr = (size_t)NB*48;
    const int NQ = NT/4;

    auto STEP = [&](u32 px0, u32 px1, u32 px2){
        float z0=cEb[0], z1=cEb[1], z2=cEb[2], z3=cEb[3];
        z0=dot2u(wd[0][0],px0,z0); z0=dot2u(wd[0][1],px1,z0); z0=dot2u(wd[0][2],px2,z0);
        z0=dot2u(wd[0][3],d01,z0); z0=dot2u(wd[0][4],d23,z0); z0=dot2u(wd[0][5],d45,z0);
        z1=dot2u(wd[1][0],px0,z1); z1=dot2u(wd[1][1],px1,z1); z1=dot2u(wd[1][2],px2,z1);
        z1=dot2u(wd[1][3],d01,z1); z1=dot2u(wd[1][4],d23,z1); z1=dot2u(wd[1][5],d45,z1);
        z2=dot2u(wd[2][0],px0,z2); z2=dot2u(wd[2][1],px1,z2); z2=dot2u(wd[2][2],px2,z2);
        z2=dot2u(wd[2][3],d01,z2); z2=dot2u(wd[2][4],d23,z2); z2=dot2u(wd[2][5],d45,z2);
        z3=dot2u(wd[3][0],px0,z3); z3=dot2u(wd[3][1],px1,z3); z3=dot2u(wd[3][2],px2,z3);
        z3=dot2u(wd[3][3],d01,z3); z3=dot2u(wd[3][4],d23,z3); z3=dot2u(wd[3][5],d45,z3);
        const float iv = rcp_(1.0f + exp2_(z0));
        const float fv = rcp_(1.0f + exp2_(z1));
        const float gv = fmaf(2.0f, rcp_(1.0f + exp2_(z2)), -1.0f);
        const float ov = rcp_(1.0f + exp2_(z3));
        cc = fmaf(fv, cc, iv*gv);
        hn = ov * tanh_(cc);
        BCAST(hn, d01, d23, d45);
    };

    // x for a quad: 24 floats = 6 f32x4. Step s uses floats [6s..6s+5].
    f32x4 xA[6], xB[6];
    auto ldg = [&](int q, f32x4* d){
        const f32x4* p = (const f32x4*)(xb + (size_t)q*96);
#pragma unroll
        for (int k=0;k<6;++k) d[k]=p[k];
    };

    u32 s01[4], s23[4], s45[4];
    auto DO_STEP = [&](const f32x4* d, int s, int slot){
        // floats 6s..6s+5 from d[]: even s -> d[3s/2].xyzw + d[3s/2+1].xy
        //                            odd  s -> d[(3s-1)/2].zw + d[(3s+1)/2].xyzw
        u32 p0,p1,p2;
        if ((s & 1) == 0){
            const f32x4 a = d[(3*s)>>1], c2 = d[((3*s)>>1)+1];
            p0 = pkrtz(a.x,a.y); p1 = pkrtz(a.z,a.w); p2 = pkrtz(c2.x,c2.y);
        } else {
            const f32x4 a = d[(3*s-1)>>1], c2 = d[((3*s-1)>>1)+1];
            p0 = pkrtz(a.z,a.w); p1 = pkrtz(c2.x,c2.y); p2 = pkrtz(c2.z,c2.w);
        }
        STEP(p0,p1,p2);
        s01[slot]=d01; s23[slot]=d23; s45[slot]=d45;
    };

    auto GROUP = [&](const f32x4* d, int q){
        if (!dir){
            DO_STEP(d,0,0); DO_STEP(d,1,1); DO_STEP(d,2,2); DO_STEP(d,3,3);
        } else {
            DO_STEP(d,3,3); DO_STEP(d,2,2); DO_STEP(d,1,1); DO_STEP(d,0,0);
        }
        if (j < 3){
            const u32* s = (j==0)?s01:((j==1)?s23:s45);
            u32x4 v; v.x=s[0]; v.y=s[1]; v.z=s[2]; v.w=s[3];
            *(u32x4*)(obase + (size_t)q*qstr) = v;
        }
    };

    const int dq = dir ? -1 : 1;
    int q = dir ? (NQ-1) : 0;
    {
        int q1 = q+dq; q1 = q1<0?0:(q1>NQ-1?NQ-1:q1);
        ldg(q, xA); ldg(q1, xB);
    }
    for (int it=0; it<NQ; it+=2){
        GROUP(xA, q);
        { int qn=q+2*dq; qn = qn<0?0:(qn>NQ-1?NQ-1:qn); ldg(qn, xA); }
        q += dq;
        GROUP(xB, q);
        { int qn=q+2*dq; qn = qn<0?0:(qn>NQ-1?NQ-1:qn); ldg(qn, xB); }
        q += dq;
    }
}

// Layer 1 forward scan + r1 single step + FC head. 1024 blocks x 64.
__global__ __launch_bounds__(64)
__attribute__((amdgpu_waves_per_eu(1,1)))
void lstm_l1v3(
    const char* __restrict__ fbuf, const char* __restrict__ bbuf,
    const float* __restrict__ h0, const float* __restrict__ c0,
    const float* __restrict__ W1f, const float* __restrict__ U1f, const float* __restrict__ b1f,
    const float* __restrict__ W1b, const float* __restrict__ U1b, const float* __restrict__ b1b,
    const float* __restrict__ fcw, const float* __restrict__ fcb,
    float* __restrict__ out)
{
    const int l  = threadIdx.x;
    const int j  = l & 7;
    const int jj = (j < 6) ? j : (j - 2);
    const bool hi4 = (j & 4) != 0;
    const int b  = blockIdx.x*8 + (l >> 3);

    u32 wd1[4][9]; float cEb[4];
#pragma unroll
    for (int g=0; g<4; ++g){
        const int row = g*6 + jj;
        const float cs = (g==2) ? -2.88539008177792681f : -1.44269504088896341f;
#pragma unroll
        for (int k=0;k<3;++k) wd1[g][k]   = pkrtz(cs*W1f[row*12+2*k],   cs*W1f[row*12+2*k+1]);
#pragma unroll
        for (int k=0;k<3;++k) wd1[g][3+k] = pkrtz(cs*W1f[row*12+6+2*k], cs*W1f[row*12+6+2*k+1]);
#pragma unroll
        for (int k=0;k<3;++k) wd1[g][6+k] = pkrtz(cs*U1f[row*6+2*k],    cs*U1f[row*6+2*k+1]);
        cEb[g] = cs * b1f[row];
    }
#pragma unroll
    for (int g=0; g<4; ++g){
#pragma unroll
        for (int k=0;k<9;++k) PINF(wd1[g][k]);
        PINF(cEb[g]);
    }

    float cc = c0[2*(NB*6) + b*6 + jj];
    float hn = h0[2*(NB*6) + b*6 + jj];
    u32 d01, d23, d45;
    BCAST(hn, d01, d23, d45);

    const char* fp = fbuf + (size_t)b*48;
    const char* rp = bbuf + (size_t)b*48;
    const size_t qstr = (size_t)NB*48;
    const int NQ = NT/4;

    auto STEP = [&](u32 f0d, u32 f1d, u32 f2d, u32 r0d, u32 r1d, u32 r2d){
        float z0=cEb[0], z1=cEb[1], z2=cEb[2], z3=cEb[3];
        z0=dot2u(wd1[0][0],f0d,z0); z0=dot2u(wd1[0][1],f1d,z0); z0=dot2u(wd1[0][2],f2d,z0);
        z0=dot2u(wd1[0][3],r0d,z0); z0=dot2u(wd1[0][4],r1d,z0); z0=dot2u(wd1[0][5],r2d,z0);
        z0=dot2u(wd1[0][6],d01,z0); z0=dot2u(wd1[0][7],d23,z0); z0=dot2u(wd1[0][8],d45,z0);
        z1=dot2u(wd1[1][0],f0d,z1); z1=dot2u(wd1[1][1],f1d,z1); z1=dot2u(wd1[1][2],f2d,z1);
        z1=dot2u(wd1[1][3],r0d,z1); z1=dot2u(wd1[1][4],r1d,z1); z1=dot2u(wd1[1][5],r2d,z1);
        z1=dot2u(wd1[1][6],d01,z1); z1=dot2u(wd1[1][7],d23,z1); z1=dot2u(wd1[1][8],d45,z1);
        z2=dot2u(wd1[2][0],f0d,z2); z2=dot2u(wd1[2][1],f1d,z2); z2=dot2u(wd1[2][2],f2d,z2);
        z2=dot2u(wd1[2][3],r0d,z2); z2=dot2u(wd1[2][4],r1d,z2); z2=dot2u(wd1[2][5],r2d,z2);
        z2=dot2u(wd1[2][6],d01,z2); z2=dot2u(wd1[2][7],d23,z2); z2=dot2u(wd1[2][8],d45,z2);
        z3=dot2u(wd1[3][0],f0d,z3); z3=dot2u(wd1[3][1],f1d,z3); z3=dot2u(wd1[3][2],f2d,z3);
        z3=dot2u(wd1[3][3],r0d,z3); z3=dot2u(wd1[3][4],r1d,z3); z3=dot2u(wd1[3][5],r2d,z3);
        z3=dot2u(wd1[3][6],d01,z3); z3=dot2u(wd1[3][7],d23,z3); z3=dot2u(wd1[3][8],d45,z3);
        const float iv = rcp_(1.0f + exp2_(z0));
        const float fv = rcp_(1.0f + exp2_(z1));
        const float gv = fmaf(2.0f, rcp_(1.0f + exp2_(z2)), -1.0f);
        const float ov = rcp_(1.0f + exp2_(z3));
        cc = fmaf(fv, cc, iv*gv);
        hn = ov * tanh_(cc);
        BCAST(hn, d01, d23, d45);
    };

    u32x4 FA[3], RA[3], FB[3], RB[3];
    auto ldq = [&](int q, u32x4* F, u32x4* R){
        const u32x4* f = (const u32x4*)(fp + (size_t)q*qstr);
        const u32x4* r = (const u32x4*)(rp + (size_t)q*qstr);
        F[0]=f[0]; F[1]=f[1]; F[2]=f[2];
        R[0]=r[0]; R[1]=r[1]; R[2]=r[2];
    };
    auto GROUP = [&](const u32x4* F, const u32x4* R){
        STEP(F[0].x, F[1].x, F[2].x, R[0].x, R[1].x, R[2].x);
        STEP(F[0].y, F[1].y, F[2].y, R[0].y, R[1].y, R[2].y);
        STEP(F[0].z, F[1].z, F[2].z, R[0].z, R[1].z, R[2].z);
        STEP(F[0].w, F[1].w, F[2].w, R[0].w, R[1].w, R[2].w);
    };

    ldq(0, FA, RA); ldq(1, FB, RB);
    for (int q=0; q<NQ; q+=2){
        GROUP(FA, RA);
        { int qn=q+2; qn = qn>NQ-1?NQ-1:qn; ldq(qn, FA, RA); }
        GROUP(FB, RB);
        { int qn=q+3; qn = qn>NQ-1?NQ-1:qn; ldq(qn, FB, RB); }
    }
    // hn = h1[511]; FB/RB hold quad NQ-1 (t=508..511)

    // ---- l0[511] as f32 (t=511 = .w lanes of quad NQ-1) ----
    float v[12];
#pragma unroll
    for (int k=0;k<3;++k){
        v[2*k]   = upk_lo(FB[k].w);  v[2*k+1]   = upk_hi(FB[k].w);
        v[6+2*k] = upk_lo(RB[k].w);  v[7+2*k]   = upk_hi(RB[k].w);
    }

    // ---- r1: single reverse-direction step at t = NT-1 (f32 math) ----
    const int base3 = 3*(NB*6) + b*6;
    float hr6[6];
#pragma unroll
    for (int k=0;k<6;++k) hr6[k] = h0[base3 + k];
    float cr = c0[base3 + jj];

    float zr[4];
#pragma unroll
    for (int g=0; g<4; ++g){
        const int row = g*6 + jj;
        float acc = b1b[row];
#pragma unroll
        for (int k=0;k<12;++k) acc = fmaf(W1b[row*12+k], v[k], acc);
#pragma unroll
        for (int k=0;k<6;++k)  acc = fmaf(U1b[row*6+k], hr6[k], acc);
        zr[g] = acc;
    }
    {
        const float iv = sigm(zr[0]);
        const float fv = sigm(zr[1]);
        const float gv = tanh_(zr[2]);
        cr = fmaf(fv, cr, iv*gv);
    }
    const float hrv = sigm(zr[3]) * tanh_(cr);

    // ---- head: out[b][j] = fcb[j] + fcw[j] . relu([h1; r1]) ----
    float u[12];
    u[0]=fmaxf(swzbc<0>(hn),0.f); u[1]=fmaxf(swzbc<1>(hn),0.f); u[2]=fmaxf(swzbc<2>(hn),0.f);
    u[3]=fmaxf(swzbc<3>(hn),0.f); u[4]=fmaxf(swzbc<4>(hn),0.f); u[5]=fmaxf(swzbc<5>(hn),0.f);
    u[6]=fmaxf(swzbc<0>(hrv),0.f); u[7]=fmaxf(swzbc<1>(hrv),0.f); u[8]=fmaxf(swzbc<2>(hrv),0.f);
    u[9]=fmaxf(swzbc<3>(hrv),0.f); u[10]=fmaxf(swzbc<4>(hrv),0.f); u[11]=fmaxf(swzbc<5>(hrv),0.f);
    if (j < 6){
        float acc = fcb[j];
#pragma unroll
        for (int k=0;k<12;++k) acc = fmaf(fcw[j*12+k], u[k], acc);
        out[b*6 + j] = acc;
    }
}

extern "C" void kernel_launch(void* const* d_in, const int* in_sizes, int n_in,
                              void* d_out, int out_size, void* d_ws, size_t ws_size,
                              hipStream_t stream)
{
    (void)in_sizes; (void)n_in; (void)out_size; (void)ws_size;
    const float* x    = (const float*)d_in[0];
    const float* h0   = (const float*)d_in[1];
    const float* c0   = (const float*)d_in[2];
    const float* W0f  = (const float*)d_in[3];
    const float* U0f  = (const float*)d_in[4];
    const float* b0f  = (const float*)d_in[5];
    const float* W0b  = (const float*)d_in[6];
    const float* U0b  = (const float*)d_in[7];
    const float* b0b  = (const float*)d_in[8];
    const float* W1f  = (const float*)d_in[9];
    const float* U1f  = (const float*)d_in[10];
    const float* b1f  = (const float*)d_in[11];
    const float* W1b  = (const float*)d_in[12];
    const float* U1b  = (const float*)d_in[13];
    const float* b1b  = (const float*)d_in[14];
    const float* fcw  = (const float*)d_in[15];
    const float* fcb  = (const float*)d_in[16];
    float* out = (float*)d_out;
    char* ws = (char*)d_ws;

    char* fbuf = ws;
    char* bbuf = ws + (size_t)(NT/4)*NB*48;   // 2 x 50.3 MB

    lstm_l0v3<<<dim3(2048), dim3(64), 0, stream>>>(x, h0, c0, W0f, U0f, b0f, W0b, U0b, b0b, fbuf, bbuf);
    lstm_l1v3<<<dim3(1024), dim3(64), 0, stream>>>(fbuf, bbuf, h0, c0,
        W1f, U1f, b1f, W1b, U1b, b1b, fcw, fcb, out);
}

// Round 22
// 279.777 us; speedup vs baseline: 5.5900x; 5.5900x over previous
//
#include <hip/hip_runtime.h>

#define NB 8192
#define NT 512

typedef unsigned int u32;
typedef unsigned short u16;
typedef float f32x4 __attribute__((ext_vector_type(4)));
typedef u32 u32x2 __attribute__((ext_vector_type(2)));
typedef _Float16 h16x2 __attribute__((ext_vector_type(2)));

__device__ __forceinline__ float rcp_(float x){ return __builtin_amdgcn_rcpf(x); }
__device__ __forceinline__ float exp2_(float x){ return __builtin_amdgcn_exp2f(x); }
__device__ __forceinline__ float tanh_(float x){ return 1.0f - 2.0f*rcp_(1.0f + exp2_(2.88539008177792681f*x)); }
__device__ __forceinline__ float sigm(float x){ return rcp_(1.0f + exp2_(-1.44269504088896341f*x)); }

#define PINF(v)  asm volatile("" : "+v"(v))

// quad_perm DPP (dst lane k reads src lane p_k within its quad)
#define QP_XOR1 0xB1   // [1,0,3,2]
#define QP_BC0  0x00   // all read quad-lane 0
#define QP_BC2  0xAA   // all read quad-lane 2
template<int C>
__device__ __forceinline__ u32 dppu(u32 x){
    return (u32)__builtin_amdgcn_update_dpp(0, (int)x, C, 0xF, 0xF, true);
}
__device__ __forceinline__ float dpp_xor1(float x){
    return __int_as_float(__builtin_amdgcn_update_dpp(0, __float_as_int(x), QP_XOR1, 0xF, 0xF, true));
}
// lane^4 exchange, pure VALU (validated R10/R11/R12)
__device__ __forceinline__ u32 swz4u(u32 x){
    int v = __builtin_amdgcn_update_dpp((int)x, (int)x, 0x104, 0xF, 0x5, false);
    v     = __builtin_amdgcn_update_dpp(v,      (int)x, 0x114, 0xF, 0xA, false);
    return (u32)v;
}
// group8 broadcast via LDS swizzle (validated R17) — cold epilogue only
template<int J>
__device__ __forceinline__ float swzbc(float x){
    return __int_as_float(__builtin_amdgcn_ds_swizzle(__float_as_int(x), (J<<5)|0x18));
}

__device__ __forceinline__ float upkh(u16 v){ _Float16 h; __builtin_memcpy(&h,&v,2); return (float)h; }
__device__ __forceinline__ float upk_lo(u32 v){ return upkh((u16)(v&0xffffu)); }
__device__ __forceinline__ float upk_hi(u32 v){ return upkh((u16)(v>>16)); }
__device__ __forceinline__ u32 pkrtz(float a, float b){
    auto p = __builtin_amdgcn_cvt_pkrtz(a, b);
    return __builtin_bit_cast(u32, p);
}
__device__ __forceinline__ float dot2f(h16x2 a, h16x2 b, float c){
#if __has_builtin(__builtin_amdgcn_fdot2)
    return __builtin_amdgcn_fdot2(a, b, c, false);
#else
    return fmaf((float)a.x, (float)b.x, fmaf((float)a.y, (float)b.y, c));
#endif
}
__device__ __forceinline__ float dot2u(u32 w, u32 d, float c){
    return dot2f(__builtin_bit_cast(h16x2, w), __builtin_bit_cast(h16x2, d), c);
}

// ---------------------------------------------------------------------------
// Lane-local-gates (R17) + PURE-VALU broadcast (isolated this round):
//   hp = pkrtz(hn, dpp_xor1(hn))   // lanes 0/2/4(/6): pairs A=(h0,h1)/B/C/C
//   u = QP_BC0(hp)  -> lanes0-3: A, lanes4-7: C
//   v = QP_BC2(hp)  -> lanes0-3: B, lanes4-7: C
//   w = swz4(u)     -> lanes0-3: C, lanes4-7: A
//   z = swz4(v)     -> lanes0-3: C, lanes4-7: B
//   d01 = hi4?w:u ; d23 = hi4?z:v ; d45 = hi4?u:w     (hi4 = lane&4)
// Zero LDS ops on the recurrence chain. All named scalars (no spillable
// arrays — R21's quad-batch s[slot] arrays went to scratch and 5x'd runtime).
// Buffer per (t-pair, seq): [h01@E, h01@O, h23@E, h23@O, h45@E, h45@O] fp16.
// ---------------------------------------------------------------------------

#define BCAST(hn, d01, d23, d45) do{                     \
    const float _hx = dpp_xor1(hn);                      \
    const u32 _hp = pkrtz((hn), _hx);                    \
    const u32 _u = dppu<QP_BC0>(_hp);                    \
    const u32 _v = dppu<QP_BC2>(_hp);                    \
    const u32 _w = swz4u(_u);                            \
    const u32 _z = swz4u(_v);                            \
    d01 = hi4 ? _w : _u;                                 \
    d23 = hi4 ? _z : _v;                                 \
    d45 = hi4 ? _u : _w;                                 \
}while(0)

// Layer 0, both directions. 2048 blocks x 64 = 2048 waves (2/SIMD).
__global__ __launch_bounds__(64)
__attribute__((amdgpu_waves_per_eu(2,2)))
void lstm_l0v2(
    const float* __restrict__ x,
    const float* __restrict__ h0, const float* __restrict__ c0,
    const float* __restrict__ Wf, const float* __restrict__ Uf, const float* __restrict__ bf,
    const float* __restrict__ Wb, const float* __restrict__ Ub, const float* __restrict__ bbv,
    char* __restrict__ fbuf, char* __restrict__ bbuf)
{
    const int l  = threadIdx.x;
    const int j  = l & 7;
    const int jj = (j < 6) ? j : (j - 2);
    const bool hi4 = (j & 4) != 0;
    const int e  = blockIdx.x*8 + (l >> 3);
    const int b  = e & (NB-1);
    const int dir = e >> 13;

    const float* W  = dir ? Wb  : Wf;
    const float* U  = dir ? Ub  : Uf;
    const float* bi = dir ? bbv : bf;

    u32 wd[4][6]; float cEb[4];
#pragma unroll
    for (int g=0; g<4; ++g){
        const int row = g*6 + jj;
        const float cs = (g==2) ? -2.88539008177792681f : -1.44269504088896341f;
#pragma unroll
        for (int k=0;k<3;++k) wd[g][k]   = pkrtz(cs*W[row*6+2*k], cs*W[row*6+2*k+1]);
#pragma unroll
        for (int k=0;k<3;++k) wd[g][3+k] = pkrtz(cs*U[row*6+2*k], cs*U[row*6+2*k+1]);
        cEb[g] = cs * bi[row];
    }
#pragma unroll
    for (int g=0; g<4; ++g){
#pragma unroll
        for (int k=0;k<6;++k) PINF(wd[g][k]);
        PINF(cEb[g]);
    }

    float cc = c0[dir*(NB*6) + b*6 + jj];
    float hn = h0[dir*(NB*6) + b*6 + jj];
    u32 d01, d23, d45;
    BCAST(hn, d01, d23, d45);

    const char* xb = (const char*)(x + (size_t)b*(NT*6));
    char* obase = (dir ? bbuf : fbuf) + (size_t)b*24 + j*8;   // used when j<3
    const size_t tstr = (size_t)NB*24;

    auto STEP = [&](u32 px0, u32 px1, u32 px2){
        float z0=cEb[0], z1=cEb[1], z2=cEb[2], z3=cEb[3];
        z0=dot2u(wd[0][0],px0,z0); z0=dot2u(wd[0][1],px1,z0); z0=dot2u(wd[0][2],px2,z0);
        z0=dot2u(wd[0][3],d01,z0); z0=dot2u(wd[0][4],d23,z0); z0=dot2u(wd[0][5],d45,z0);
        z1=dot2u(wd[1][0],px0,z1); z1=dot2u(wd[1][1],px1,z1); z1=dot2u(wd[1][2],px2,z1);
        z1=dot2u(wd[1][3],d01,z1); z1=dot2u(wd[1][4],d23,z1); z1=dot2u(wd[1][5],d45,z1);
        z2=dot2u(wd[2][0],px0,z2); z2=dot2u(wd[2][1],px1,z2); z2=dot2u(wd[2][2],px2,z2);
        z2=dot2u(wd[2][3],d01,z2); z2=dot2u(wd[2][4],d23,z2); z2=dot2u(wd[2][5],d45,z2);
        z3=dot2u(wd[3][0],px0,z3); z3=dot2u(wd[3][1],px1,z3); z3=dot2u(wd[3][2],px2,z3);
        z3=dot2u(wd[3][3],d01,z3); z3=dot2u(wd[3][4],d23,z3); z3=dot2u(wd[3][5],d45,z3);
        const float iv = rcp_(1.0f + exp2_(z0));
        const float fv = rcp_(1.0f + exp2_(z1));
        const float gv = fmaf(2.0f, rcp_(1.0f + exp2_(z2)), -1.0f);
        const float ov = rcp_(1.0f + exp2_(z3));
        cc = fmaf(fv, cc, iv*gv);
        hn = ov * tanh_(cc);
        BCAST(hn, d01, d23, d45);
    };

    f32x4 xA[3], xB[3];
    auto ldg = [&](int p, f32x4* d){
        const f32x4* q = (const f32x4*)(xb + (size_t)p*48);
        d[0]=q[0]; d[1]=q[1]; d[2]=q[2];
    };

    auto GROUP = [&](const f32x4* d, int p){
        u32 e0,e1,e2,o0,o1,o2;
        if (!dir){
            STEP(pkrtz(d[0].x,d[0].y), pkrtz(d[0].z,d[0].w), pkrtz(d[1].x,d[1].y));
            e0=d01; e1=d23; e2=d45;
            STEP(pkrtz(d[1].z,d[1].w), pkrtz(d[2].x,d[2].y), pkrtz(d[2].z,d[2].w));
            o0=d01; o1=d23; o2=d45;
        } else {
            STEP(pkrtz(d[1].z,d[1].w), pkrtz(d[2].x,d[2].y), pkrtz(d[2].z,d[2].w));
            o0=d01; o1=d23; o2=d45;
            STEP(pkrtz(d[0].x,d[0].y), pkrtz(d[0].z,d[0].w), pkrtz(d[1].x,d[1].y));
            e0=d01; e1=d23; e2=d45;
        }
        if (j < 3){
            const u32 se = (j==0)?e0:((j==1)?e1:e2);
            const u32 so = (j==0)?o0:((j==1)?o1:o2);
            u32x2 v; v.x=se; v.y=so;
            *(u32x2*)(obase + (size_t)p*tstr) = v;
        }
    };

    const int dp = dir ? -1 : 1;
    int p = dir ? (NT/2-1) : 0;
    {
        int p1 = p+dp; p1 = p1<0?0:(p1>NT/2-1?NT/2-1:p1);
        ldg(p, xA); ldg(p1, xB);
    }
    for (int it=0; it<NT/2; it+=2){
        GROUP(xA, p);
        { int pn=p+2*dp; pn = pn<0?0:(pn>NT/2-1?NT/2-1:pn); ldg(pn, xA); }
        p += dp;
        GROUP(xB, p);
        { int pn=p+2*dp; pn = pn<0?0:(pn>NT/2-1?NT/2-1:pn); ldg(pn, xB); }
        p += dp;
    }
}

// Layer 1 forward scan + r1 single step + FC head. 1024 blocks x 64.
__global__ __launch_bounds__(64)
__attribute__((amdgpu_waves_per_eu(1,1)))
void lstm_l1v2(
    const char* __restrict__ fbuf, const char* __restrict__ bbuf,
    const float* __restrict__ h0, const float* __restrict__ c0,
    const float* __restrict__ W1f, const float* __restrict__ U1f, const float* __restrict__ b1f,
    const float* __restrict__ W1b, const float* __restrict__ U1b, const float* __restrict__ b1b,
    const float* __restrict__ fcw, const float* __restrict__ fcb,
    float* __restrict__ out)
{
    const int l  = threadIdx.x;
    const int j  = l & 7;
    const int jj = (j < 6) ? j : (j - 2);
    const bool hi4 = (j & 4) != 0;
    const int b  = blockIdx.x*8 + (l >> 3);

    u32 wd1[4][9]; float cEb[4];
#pragma unroll
    for (int g=0; g<4; ++g){
        const int row = g*6 + jj;
        const float cs = (g==2) ? -2.88539008177792681f : -1.44269504088896341f;
#pragma unroll
        for (int k=0;k<3;++k) wd1[g][k]   = pkrtz(cs*W1f[row*12+2*k],   cs*W1f[row*12+2*k+1]);
#pragma unroll
        for (int k=0;k<3;++k) wd1[g][3+k] = pkrtz(cs*W1f[row*12+6+2*k], cs*W1f[row*12+6+2*k+1]);
#pragma unroll
        for (int k=0;k<3;++k) wd1[g][6+k] = pkrtz(cs*U1f[row*6+2*k],    cs*U1f[row*6+2*k+1]);
        cEb[g] = cs * b1f[row];
    }
#pragma unroll
    for (int g=0; g<4; ++g){
#pragma unroll
        for (int k=0;k<9;++k) PINF(wd1[g][k]);
        PINF(cEb[g]);
    }

    float cc = c0[2*(NB*6) + b*6 + jj];
    float hn = h0[2*(NB*6) + b*6 + jj];
    u32 d01, d23, d45;
    BCAST(hn, d01, d23, d45);

    const char* fp = fbuf + (size_t)b*24;
    const char* rp = bbuf + (size_t)b*24;
    const size_t tstr = (size_t)NB*24;

    auto STEP = [&](u32 f0d, u32 f1d, u32 f2d, u32 r0d, u32 r1d, u32 r2d){
        float z0=cEb[0], z1=cEb[1], z2=cEb[2], z3=cEb[3];
        z0=dot2u(wd1[0][0],f0d,z0); z0=dot2u(wd1[0][1],f1d,z0); z0=dot2u(wd1[0][2],f2d,z0);
        z0=dot2u(wd1[0][3],r0d,z0); z0=dot2u(wd1[0][4],r1d,z0); z0=dot2u(wd1[0][5],r2d,z0);
        z0=dot2u(wd1[0][6],d01,z0); z0=dot2u(wd1[0][7],d23,z0); z0=dot2u(wd1[0][8],d45,z0);
        z1=dot2u(wd1[1][0],f0d,z1); z1=dot2u(wd1[1][1],f1d,z1); z1=dot2u(wd1[1][2],f2d,z1);
        z1=dot2u(wd1[1][3],r0d,z1); z1=dot2u(wd1[1][4],r1d,z1); z1=dot2u(wd1[1][5],r2d,z1);
        z1=dot2u(wd1[1][6],d01,z1); z1=dot2u(wd1[1][7],d23,z1); z1=dot2u(wd1[1][8],d45,z1);
        z2=dot2u(wd1[2][0],f0d,z2); z2=dot2u(wd1[2][1],f1d,z2); z2=dot2u(wd1[2][2],f2d,z2);
        z2=dot2u(wd1[2][3],r0d,z2); z2=dot2u(wd1[2][4],r1d,z2); z2=dot2u(wd1[2][5],r2d,z2);
        z2=dot2u(wd1[2][6],d01,z2); z2=dot2u(wd1[2][7],d23,z2); z2=dot2u(wd1[2][8],d45,z2);
        z3=dot2u(wd1[3][0],f0d,z3); z3=dot2u(wd1[3][1],f1d,z3); z3=dot2u(wd1[3][2],f2d,z3);
        z3=dot2u(wd1[3][3],r0d,z3); z3=dot2u(wd1[3][4],r1d,z3); z3=dot2u(wd1[3][5],r2d,z3);
        z3=dot2u(wd1[3][6],d01,z3); z3=dot2u(wd1[3][7],d23,z3); z3=dot2u(wd1[3][8],d45,z3);
        const float iv = rcp_(1.0f + exp2_(z0));
        const float fv = rcp_(1.0f + exp2_(z1));
        const float gv = fmaf(2.0f, rcp_(1.0f + exp2_(z2)), -1.0f);
        const float ov = rcp_(1.0f + exp2_(z3));
        cc = fmaf(fv, cc, iv*gv);
        hn = ov * tanh_(cc);
        BCAST(hn, d01, d23, d45);
    };

    u32x2 FA[3], RA[3], FB[3], RB[3];
    auto ldp = [&](int p, u32x2* F, u32x2* R){
        const u32x2* f = (const u32x2*)(fp + (size_t)p*tstr);
        const u32x2* r = (const u32x2*)(rp + (size_t)p*tstr);
        F[0]=f[0]; F[1]=f[1]; F[2]=f[2];
        R[0]=r[0]; R[1]=r[1]; R[2]=r[2];
    };
    auto GROUP = [&](const u32x2* F, const u32x2* R){
        STEP(F[0].x, F[1].x, F[2].x, R[0].x, R[1].x, R[2].x);
        STEP(F[0].y, F[1].y, F[2].y, R[0].y, R[1].y, R[2].y);
    };

    ldp(0, FA, RA); ldp(1, FB, RB);
    for (int p=0; p<NT/2; p+=2){
        GROUP(FA, RA);
        { int pn=p+2; pn = pn>NT/2-1?NT/2-1:pn; ldp(pn, FA, RA); }
        GROUP(FB, RB);
        { int pn=p+3; pn = pn>NT/2-1?NT/2-1:pn; ldp(pn, FB, RB); }
    }
    // hn = h1[511] (f32, lane j = hidden jj)

    // ---- l0[511] as f32 (odd dwords of pair 255) ----
    float v[12];
    {
        const char* f255 = fp + (size_t)(NT/2-1)*tstr;
        const char* r255 = rp + (size_t)(NT/2-1)*tstr;
#pragma unroll
        for (int k=0;k<3;++k){
            const u32 fd = *(const u32*)(f255 + k*8 + 4);
            const u32 rd = *(const u32*)(r255 + k*8 + 4);
            v[2*k]   = upk_lo(fd);  v[2*k+1]   = upk_hi(fd);
            v[6+2*k] = upk_lo(rd);  v[6+2*k+1] = upk_hi(rd);
        }
    }

    // ---- r1: single reverse-direction step at t = NT-1 (f32 math) ----
    const int base3 = 3*(NB*6) + b*6;
    float hr6[6];
#pragma unroll
    for (int k=0;k<6;++k) hr6[k] = h0[base3 + k];
    float cr = c0[base3 + jj];

    float zr[4];
#pragma unroll
    for (int g=0; g<4; ++g){
        const int row = g*6 + jj;
        float acc = b1b[row];
#pragma unroll
        for (int k=0;k<12;++k) acc = fmaf(W1b[row*12+k], v[k], acc);
#pragma unroll
        for (int k=0;k<6;++k)  acc = fmaf(U1b[row*6+k], hr6[k], acc);
        zr[g] = acc;
    }
    {
        const float iv = sigm(zr[0]);
        const float fv = sigm(zr[1]);
        const float gv = tanh_(zr[2]);
        cr = fmaf(fv, cr, iv*gv);
    }
    const float hrv = sigm(zr[3]) * tanh_(cr);

    // ---- head: out[b][j] = fcb[j] + fcw[j] . relu([h1; r1]) ----
    float u[12];
    u[0]=fmaxf(swzbc<0>(hn),0.f); u[1]=fmaxf(swzbc<1>(hn),0.f); u[2]=fmaxf(swzbc<2>(hn),0.f);
    u[3]=fmaxf(swzbc<3>(hn),0.f); u[4]=fmaxf(swzbc<4>(hn),0.f); u[5]=fmaxf(swzbc<5>(hn),0.f);
    u[6]=fmaxf(swzbc<0>(hrv),0.f); u[7]=fmaxf(swzbc<1>(hrv),0.f); u[8]=fmaxf(swzbc<2>(hrv),0.f);
    u[9]=fmaxf(swzbc<3>(hrv),0.f); u[10]=fmaxf(swzbc<4>(hrv),0.f); u[11]=fmaxf(swzbc<5>(hrv),0.f);
    if (j < 6){
        float acc = fcb[j];
#pragma unroll
        for (int k=0;k<12;++k) acc = fmaf(fcw[j*12+k], u[k], acc);
        out[b*6 + j] = acc;
    }
}

extern "C" void kernel_launch(void* const* d_in, const int* in_sizes, int n_in,
                              void* d_out, int out_size, void* d_ws, size_t ws_size,
                              hipStream_t stream)
{
    (void)in_sizes; (void)n_in; (void)out_size; (void)ws_size;
    const float* x    = (const float*)d_in[0];
    const float* h0   = (const float*)d_in[1];
    const float* c0   = (const float*)d_in[2];
    const float* W0f  = (const float*)d_in[3];
    const float* U0f  = (const float*)d_in[4];
    const float* b0f  = (const float*)d_in[5];
    const float* W0b  = (const float*)d_in[6];
    const float* U0b  = (const float*)d_in[7];
    const float* b0b  = (const float*)d_in[8];
    const float* W1f  = (const float*)d_in[9];
    const float* U1f  = (const float*)d_in[10];
    const float* b1f  = (const float*)d_in[11];
    const float* W1b  = (const float*)d_in[12];
    const float* U1b  = (const float*)d_in[13];
    const float* b1b  = (const float*)d_in[14];
    const float* fcw  = (const float*)d_in[15];
    const float* fcb  = (const float*)d_in[16];
    float* out = (float*)d_out;
    char* ws = (char*)d_ws;

    char* fbuf = ws;
    char* bbuf = ws + (size_t)(NT/2)*NB*24;   // 2 x 50.3 MB

    lstm_l0v2<<<dim3(2048), dim3(64), 0, stream>>>(x, h0, c0, W0f, U0f, b0f, W0b, U0b, b0b, fbuf, bbuf);
    lstm_l1v2<<<dim3(1024), dim3(64), 0, stream>>>(fbuf, bbuf, h0, c0,
        W1f, U1f, b1f, W1b, U1b, b1b, fcw, fcb, out);
}

// Round 23
// 271.544 us; speedup vs baseline: 5.7595x; 1.0303x over previous
//
#include <hip/hip_runtime.h>

#define NB 8192
#define NT 512

typedef unsigned int u32;
typedef unsigned short u16;
typedef float f32x4 __attribute__((ext_vector_type(4)));
typedef u32 u32x2 __attribute__((ext_vector_type(2)));
typedef _Float16 h16x2 __attribute__((ext_vector_type(2)));

__device__ __forceinline__ float rcp_(float x){ return __builtin_amdgcn_rcpf(x); }
__device__ __forceinline__ float exp2_(float x){ return __builtin_amdgcn_exp2f(x); }
__device__ __forceinline__ float tanh_(float x){ return 1.0f - 2.0f*rcp_(1.0f + exp2_(2.88539008177792681f*x)); }
__device__ __forceinline__ float sigm(float x){ return rcp_(1.0f + exp2_(-1.44269504088896341f*x)); }

#define PINF(v)  asm volatile("" : "+v"(v))

// quad_perm xor1: [1,0,3,2]
#define QP_XOR1 0xB1
__device__ __forceinline__ float dpp_xor1(float x){
    return __int_as_float(__builtin_amdgcn_update_dpp(0, __float_as_int(x), QP_XOR1, 0xF, 0xF, true));
}

// Broadcast lane (group8_base + J) to all 8 lanes of the group (validated R17).
template<int J>
__device__ __forceinline__ float swzbc(float x){
    return __int_as_float(__builtin_amdgcn_ds_swizzle(__float_as_int(x), (J<<5)|0x18));
}
template<int J>
__device__ __forceinline__ u32 swzbcu(u32 x){
    return (u32)__builtin_amdgcn_ds_swizzle((int)x, (J<<5)|0x18);
}

__device__ __forceinline__ float upkh(u16 v){ _Float16 h; __builtin_memcpy(&h,&v,2); return (float)h; }
__device__ __forceinline__ float upk_lo(u32 v){ return upkh((u16)(v&0xffffu)); }
__device__ __forceinline__ float upk_hi(u32 v){ return upkh((u16)(v>>16)); }
__device__ __forceinline__ u32 pkrtz(float a, float b){
    auto p = __builtin_amdgcn_cvt_pkrtz(a, b);
    return __builtin_bit_cast(u32, p);
}
__device__ __forceinline__ float dot2f(h16x2 a, h16x2 b, float c){
#if __has_builtin(__builtin_amdgcn_fdot2)
    return __builtin_amdgcn_fdot2(a, b, c, false);
#else
    return fmaf((float)a.x, (float)b.x, fmaf((float)a.y, (float)b.y, c));
#endif
}
__device__ __forceinline__ float dot2u(u32 w, u32 d, float c){
    return dot2f(__builtin_bit_cast(h16x2, w), __builtin_bit_cast(h16x2, d), c);
}

// ---------------------------------------------------------------------------
// Lane-local-gates layout (validated R17): 8 lanes/seq; lane j owns hidden
// unit jj; all 4 gates lane-local. Broadcast block (validated R20):
//   hp  = pkrtz(hn, dpp_xor1(hn))      // even lanes: (h_even, h_odd) pairs
//   d01 = swzbcu<0>(hp); d23 = swzbcu<2>(hp); d45 = swzbcu<4>(hp)
// Buffer per (t-pair, seq): [h01@E, h01@O, h23@E, h23@O, h45@E, h45@O] fp16.
// ---------------------------------------------------------------------------

#define BCAST(hn, d01, d23, d45) do{                 \
    const float _hx = dpp_xor1(hn);                  \
    const u32 _hp = pkrtz((hn), _hx);                \
    d01 = swzbcu<0>(_hp);                            \
    d23 = swzbcu<2>(_hp);                            \
    d45 = swzbcu<4>(_hp);                            \
}while(0)

// Layer 0, both directions. 2048 blocks x 64 = 2048 waves (2/SIMD).
__global__ __launch_bounds__(64)
__attribute__((amdgpu_waves_per_eu(2,2)))
void lstm_l0v2(
    const float* __restrict__ x,
    const float* __restrict__ h0, const float* __restrict__ c0,
    const float* __restrict__ Wf, const float* __restrict__ Uf, const float* __restrict__ bf,
    const float* __restrict__ Wb, const float* __restrict__ Ub, const float* __restrict__ bbv,
    char* __restrict__ fbuf, char* __restrict__ bbuf)
{
    const int l  = threadIdx.x;
    const int j  = l & 7;
    const int jj = (j < 6) ? j : (j - 2);
    const int e  = blockIdx.x*8 + (l >> 3);
    const int b  = e & (NB-1);
    const int dir = e >> 13;

    const float* W  = dir ? Wb  : Wf;
    const float* U  = dir ? Ub  : Uf;
    const float* bi = dir ? bbv : bf;

    u32 wd[4][6]; float cEb[4];
#pragma unroll
    for (int g=0; g<4; ++g){
        const int row = g*6 + jj;
        const float cs = (g==2) ? -2.88539008177792681f : -1.44269504088896341f;
#pragma unroll
        for (int k=0;k<3;++k) wd[g][k]   = pkrtz(cs*W[row*6+2*k], cs*W[row*6+2*k+1]);
#pragma unroll
        for (int k=0;k<3;++k) wd[g][3+k] = pkrtz(cs*U[row*6+2*k], cs*U[row*6+2*k+1]);
        cEb[g] = cs * bi[row];
    }
#pragma unroll
    for (int g=0; g<4; ++g){
#pragma unroll
        for (int k=0;k<6;++k) PINF(wd[g][k]);
        PINF(cEb[g]);
    }

    float cc = c0[dir*(NB*6) + b*6 + jj];
    float hn = h0[dir*(NB*6) + b*6 + jj];
    u32 d01, d23, d45;
    BCAST(hn, d01, d23, d45);

    const char* xb = (const char*)(x + (size_t)b*(NT*6));
    char* obase = (dir ? bbuf : fbuf) + (size_t)b*24 + j*8;   // used when j<3
    const size_t tstr = (size_t)NB*24;

    auto STEP = [&](u32 px0, u32 px1, u32 px2){
        float z0=cEb[0], z1=cEb[1], z2=cEb[2], z3=cEb[3];
        z0=dot2u(wd[0][0],px0,z0); z0=dot2u(wd[0][1],px1,z0); z0=dot2u(wd[0][2],px2,z0);
        z0=dot2u(wd[0][3],d01,z0); z0=dot2u(wd[0][4],d23,z0); z0=dot2u(wd[0][5],d45,z0);
        z1=dot2u(wd[1][0],px0,z1); z1=dot2u(wd[1][1],px1,z1); z1=dot2u(wd[1][2],px2,z1);
        z1=dot2u(wd[1][3],d01,z1); z1=dot2u(wd[1][4],d23,z1); z1=dot2u(wd[1][5],d45,z1);
        z2=dot2u(wd[2][0],px0,z2); z2=dot2u(wd[2][1],px1,z2); z2=dot2u(wd[2][2],px2,z2);
        z2=dot2u(wd[2][3],d01,z2); z2=dot2u(wd[2][4],d23,z2); z2=dot2u(wd[2][5],d45,z2);
        z3=dot2u(wd[3][0],px0,z3); z3=dot2u(wd[3][1],px1,z3); z3=dot2u(wd[3][2],px2,z3);
        z3=dot2u(wd[3][3],d01,z3); z3=dot2u(wd[3][4],d23,z3); z3=dot2u(wd[3][5],d45,z3);
        const float iv = rcp_(1.0f + exp2_(z0));
        const float fv = rcp_(1.0f + exp2_(z1));
        const float gv = fmaf(2.0f, rcp_(1.0f + exp2_(z2)), -1.0f);
        const float ov = rcp_(1.0f + exp2_(z3));
        cc = fmaf(fv, cc, iv*gv);
        hn = ov * tanh_(cc);
        BCAST(hn, d01, d23, d45);
    };

    f32x4 xA[3], xB[3];
    auto ldg = [&](int p, f32x4* d){
        const f32x4* q = (const f32x4*)(xb + (size_t)p*48);
        d[0]=q[0]; d[1]=q[1]; d[2]=q[2];
    };

    auto GROUP = [&](const f32x4* d, int p){
        u32 e0,e1,e2,o0,o1,o2;
        if (!dir){
            STEP(pkrtz(d[0].x,d[0].y), pkrtz(d[0].z,d[0].w), pkrtz(d[1].x,d[1].y));
            e0=d01; e1=d23; e2=d45;
            STEP(pkrtz(d[1].z,d[1].w), pkrtz(d[2].x,d[2].y), pkrtz(d[2].z,d[2].w));
            o0=d01; o1=d23; o2=d45;
        } else {
            STEP(pkrtz(d[1].z,d[1].w), pkrtz(d[2].x,d[2].y), pkrtz(d[2].z,d[2].w));
            o0=d01; o1=d23; o2=d45;
            STEP(pkrtz(d[0].x,d[0].y), pkrtz(d[0].z,d[0].w), pkrtz(d[1].x,d[1].y));
            e0=d01; e1=d23; e2=d45;
        }
        if (j < 3){
            const u32 se = (j==0)?e0:((j==1)?e1:e2);
            const u32 so = (j==0)?o0:((j==1)?o1:o2);
            u32x2 v; v.x=se; v.y=so;
            *(u32x2*)(obase + (size_t)p*tstr) = v;
        }
    };

    const int dp = dir ? -1 : 1;
    int p = dir ? (NT/2-1) : 0;
    {
        int p1 = p+dp; p1 = p1<0?0:(p1>NT/2-1?NT/2-1:p1);
        ldg(p, xA); ldg(p1, xB);
    }
    for (int it=0; it<NT/2; it+=2){
        GROUP(xA, p);
        { int pn=p+2*dp; pn = pn<0?0:(pn>NT/2-1?NT/2-1:pn); ldg(pn, xA); }
        p += dp;
        GROUP(xB, p);
        { int pn=p+2*dp; pn = pn<0?0:(pn>NT/2-1?NT/2-1:pn); ldg(pn, xB); }
        p += dp;
    }
}

// Layer 1 forward scan + r1 single step + FC head. 1024 blocks x 64.
__global__ __launch_bounds__(64)
__attribute__((amdgpu_waves_per_eu(1,1)))
void lstm_l1v2(
    const char* __restrict__ fbuf, const char* __restrict__ bbuf,
    const float* __restrict__ h0, const float* __restrict__ c0,
    const float* __restrict__ W1f, const float* __restrict__ U1f, const float* __restrict__ b1f,
    const float* __restrict__ W1b, const float* __restrict__ U1b, const float* __restrict__ b1b,
    const float* __restrict__ fcw, const float* __restrict__ fcb,
    float* __restrict__ out)
{
    const int l  = threadIdx.x;
    const int j  = l & 7;
    const int jj = (j < 6) ? j : (j - 2);
    const int b  = blockIdx.x*8 + (l >> 3);

    u32 wd1[4][9]; float cEb[4];
#pragma unroll
    for (int g=0; g<4; ++g){
        const int row = g*6 + jj;
        const float cs = (g==2) ? -2.88539008177792681f : -1.44269504088896341f;
#pragma unroll
        for (int k=0;k<3;++k) wd1[g][k]   = pkrtz(cs*W1f[row*12+2*k],   cs*W1f[row*12+2*k+1]);
#pragma unroll
        for (int k=0;k<3;++k) wd1[g][3+k] = pkrtz(cs*W1f[row*12+6+2*k], cs*W1f[row*12+6+2*k+1]);
#pragma unroll
        for (int k=0;k<3;++k) wd1[g][6+k] = pkrtz(cs*U1f[row*6+2*k],    cs*U1f[row*6+2*k+1]);
        cEb[g] = cs * b1f[row];
    }
#pragma unroll
    for (int g=0; g<4; ++g){
#pragma unroll
        for (int k=0;k<9;++k) PINF(wd1[g][k]);
        PINF(cEb[g]);
    }

    float cc = c0[2*(NB*6) + b*6 + jj];
    float hn = h0[2*(NB*6) + b*6 + jj];
    u32 d01, d23, d45;
    BCAST(hn, d01, d23, d45);

    const char* fp = fbuf + (size_t)b*24;
    const char* rp = bbuf + (size_t)b*24;
    const size_t tstr = (size_t)NB*24;

    auto STEP = [&](u32 f0d, u32 f1d, u32 f2d, u32 r0d, u32 r1d, u32 r2d){
        float z0=cEb[0], z1=cEb[1], z2=cEb[2], z3=cEb[3];
        z0=dot2u(wd1[0][0],f0d,z0); z0=dot2u(wd1[0][1],f1d,z0); z0=dot2u(wd1[0][2],f2d,z0);
        z0=dot2u(wd1[0][3],r0d,z0); z0=dot2u(wd1[0][4],r1d,z0); z0=dot2u(wd1[0][5],r2d,z0);
        z0=dot2u(wd1[0][6],d01,z0); z0=dot2u(wd1[0][7],d23,z0); z0=dot2u(wd1[0][8],d45,z0);
        z1=dot2u(wd1[1][0],f0d,z1); z1=dot2u(wd1[1][1],f1d,z1); z1=dot2u(wd1[1][2],f2d,z1);
        z1=dot2u(wd1[1][3],r0d,z1); z1=dot2u(wd1[1][4],r1d,z1); z1=dot2u(wd1[1][5],r2d,z1);
        z1=dot2u(wd1[1][6],d01,z1); z1=dot2u(wd1[1][7],d23,z1); z1=dot2u(wd1[1][8],d45,z1);
        z2=dot2u(wd1[2][0],f0d,z2); z2=dot2u(wd1[2][1],f1d,z2); z2=dot2u(wd1[2][2],f2d,z2);
        z2=dot2u(wd1[2][3],r0d,z2); z2=dot2u(wd1[2][4],r1d,z2); z2=dot2u(wd1[2][5],r2d,z2);
        z2=dot2u(wd1[2][6],d01,z2); z2=dot2u(wd1[2][7],d23,z2); z2=dot2u(wd1[2][8],d45,z2);
        z3=dot2u(wd1[3][0],f0d,z3); z3=dot2u(wd1[3][1],f1d,z3); z3=dot2u(wd1[3][2],f2d,z3);
        z3=dot2u(wd1[3][3],r0d,z3); z3=dot2u(wd1[3][4],r1d,z3); z3=dot2u(wd1[3][5],r2d,z3);
        z3=dot2u(wd1[3][6],d01,z3); z3=dot2u(wd1[3][7],d23,z3); z3=dot2u(wd1[3][8],d45,z3);
        const float iv = rcp_(1.0f + exp2_(z0));
        const float fv = rcp_(1.0f + exp2_(z1));
        const float gv = fmaf(2.0f, rcp_(1.0f + exp2_(z2)), -1.0f);
        const float ov = rcp_(1.0f + exp2_(z3));
        cc = fmaf(fv, cc, iv*gv);
        hn = ov * tanh_(cc);
        BCAST(hn, d01, d23, d45);
    };

    u32x2 FA[3], RA[3], FB[3], RB[3];
    auto ldp = [&](int p, u32x2* F, u32x2* R){
        const u32x2* f = (const u32x2*)(fp + (size_t)p*tstr);
        const u32x2* r = (const u32x2*)(rp + (size_t)p*tstr);
        F[0]=f[0]; F[1]=f[1]; F[2]=f[2];
        R[0]=r[0]; R[1]=r[1]; R[2]=r[2];
    };
    auto GROUP = [&](const u32x2* F, const u32x2* R){
        STEP(F[0].x, F[1].x, F[2].x, R[0].x, R[1].x, R[2].x);
        STEP(F[0].y, F[1].y, F[2].y, R[0].y, R[1].y, R[2].y);
    };

    ldp(0, FA, RA); ldp(1, FB, RB);
    for (int p=0; p<NT/2; p+=2){
        GROUP(FA, RA);
        { int pn=p+2; pn = pn>NT/2-1?NT/2-1:pn; ldp(pn, FA, RA); }
        GROUP(FB, RB);
        { int pn=p+3; pn = pn>NT/2-1?NT/2-1:pn; ldp(pn, FB, RB); }
    }
    // hn = h1[511] (f32, lane j = hidden jj)

    // ---- l0[511] as f32 (odd dwords of pair 255) ----
    float v[12];
    {
        const char* f255 = fp + (size_t)(NT/2-1)*tstr;
        const char* r255 = rp + (size_t)(NT/2-1)*tstr;
#pragma unroll
        for (int k=0;k<3;++k){
            const u32 fd = *(const u32*)(f255 + k*8 + 4);
            const u32 rd = *(const u32*)(r255 + k*8 + 4);
            v[2*k]   = upk_lo(fd);  v[2*k+1]   = upk_hi(fd);
            v[6+2*k] = upk_lo(rd);  v[6+2*k+1] = upk_hi(rd);
        }
    }

    // ---- r1: single reverse-direction step at t = NT-1 (f32 math) ----
    const int base3 = 3*(NB*6) + b*6;
    float hr6[6];
#pragma unroll
    for (int k=0;k<6;++k) hr6[k] = h0[base3 + k];
    float cr = c0[base3 + jj];

    float zr[4];
#pragma unroll
    for (int g=0; g<4; ++g){
        const int row = g*6 + jj;
        float acc = b1b[row];
#pragma unroll
        for (int k=0;k<12;++k) acc = fmaf(W1b[row*12+k], v[k], acc);
#pragma unroll
        for (int k=0;k<6;++k)  acc = fmaf(U1b[row*6+k], hr6[k], acc);
        zr[g] = acc;
    }
    {
        const float iv = sigm(zr[0]);
        const float fv = sigm(zr[1]);
        const float gv = tanh_(zr[2]);
        cr = fmaf(fv, cr, iv*gv);
    }
    const float hrv = sigm(zr[3]) * tanh_(cr);

    // ---- head: out[b][j] = fcb[j] + fcw[j] . relu([h1; r1]) ----
    float u[12];
    u[0]=fmaxf(swzbc<0>(hn),0.f); u[1]=fmaxf(swzbc<1>(hn),0.f); u[2]=fmaxf(swzbc<2>(hn),0.f);
    u[3]=fmaxf(swzbc<3>(hn),0.f); u[4]=fmaxf(swzbc<4>(hn),0.f); u[5]=fmaxf(swzbc<5>(hn),0.f);
    u[6]=fmaxf(swzbc<0>(hrv),0.f); u[7]=fmaxf(swzbc<1>(hrv),0.f); u[8]=fmaxf(swzbc<2>(hrv),0.f);
    u[9]=fmaxf(swzbc<3>(hrv),0.f); u[10]=fmaxf(swzbc<4>(hrv),0.f); u[11]=fmaxf(swzbc<5>(hrv),0.f);
    if (j < 6){
        float acc = fcb[j];
#pragma unroll
        for (int k=0;k<12;++k) acc = fmaf(fcw[j*12+k], u[k], acc);
        out[b*6 + j] = acc;
    }
}

extern "C" void kernel_launch(void* const* d_in, const int* in_sizes, int n_in,
                              void* d_out, int out_size, void* d_ws, size_t ws_size,
                              hipStream_t stream)
{
    (void)in_sizes; (void)n_in; (void)out_size; (void)ws_size;
    const float* x    = (const float*)d_in[0];
    const float* h0   = (const float*)d_in[1];
    const float* c0   = (const float*)d_in[2];
    const float* W0f  = (const float*)d_in[3];
    const float* U0f  = (const float*)d_in[4];
    const float* b0f  = (const float*)d_in[5];
    const float* W0b  = (const float*)d_in[6];
    const float* U0b  = (const float*)d_in[7];
    const float* b0b  = (const float*)d_in[8];
    const float* W1f  = (const float*)d_in[9];
    const float* U1f  = (const float*)d_in[10];
    const float* b1f  = (const float*)d_in[11];
    const float* W1b  = (const float*)d_in[12];
    const float* U1b  = (const float*)d_in[13];
    const float* b1b  = (const float*)d_in[14];
    const float* fcw  = (const float*)d_in[15];
    const float* fcb  = (const float*)d_in[16];
    float* out = (float*)d_out;
    char* ws = (char*)d_ws;

    char* fbuf = ws;
    char* bbuf = ws + (size_t)(NT/2)*NB*24;   // 2 x 50.3 MB

    lstm_l0v2<<<dim3(2048), dim3(64), 0, stream>>>(x, h0, c0, W0f, U0f, b0f, W0b, U0b, b0b, fbuf, bbuf);
    lstm_l1v2<<<dim3(1024), dim3(64), 0, stream>>>(fbuf, bbuf, h0, c0,
        W1f, U1f, b1f, W1b, U1b, b1b, fcw, fcb, out);
}